// Round 1
// baseline (368.431 us; speedup 1.0000x reference)
//
#include <hip/hip_runtime.h>
#include <math.h>

// Problem dims (fixed by setup_inputs): B=4, L=4096, D_MODEL=2048, HALF=32
#define M_ROWS 16384   // B*L
#define DM     2048
#define NJ     64      // 2*HALF (interleaved re/im)
#define L_SEQ  4096
#define KSPLIT 4       // K-split for Bu GEMM (parallelism: 256*4 = 1024 blocks)

// Workspace layout (float offsets). Total ~5.5M floats = 22 MB.
constexpr size_t O_CONSTS = 0;                                 // 128
constexpr size_t O_BBAR   = 128;                               // [DM][NJ]
constexpr size_t O_CC     = O_BBAR + (size_t)DM * NJ;          // [NJ][DM]
constexpr size_t O_BUP    = O_CC + (size_t)NJ * DM;            // [KSPLIT][M_ROWS][NJ]
constexpr size_t O_XS     = O_BUP + (size_t)KSPLIT * M_ROWS * NJ; // [NJ][M_ROWS]

// ---------------------------------------------------------------------------
// Kernel 0: per-state constants.
// consts[0..31]=A_re (Lam_bar re), [32..63]=A_im, [64..95]=coef_re, [96..127]=coef_im
// coef = (Lam_bar - 1) / Lam
__global__ void k_setup(const float* __restrict__ lam_ur, const float* __restrict__ lam_im,
                        const float* __restrict__ log_delta, float* __restrict__ consts) {
  int n = threadIdx.x;
  if (n < 32) {
    float x = lam_ur[n];
    float sp = (x > 20.f) ? x : log1pf(expf(x));        // softplus
    float lre = -(sp + 1.0e-4f + 0.01f);                // -(sp + EPS + NEG_BIAS)
    float lim = lam_im[n];
    float dt = expf(log_delta[n]);
    float er = expf(lre * dt);
    float Are = er * cosf(lim * dt);
    float Aim = er * sinf(lim * dt);
    float cr = Are - 1.f, ci = Aim;
    float den = lre * lre + lim * lim;
    float cre = (cr * lre + ci * lim) / den;
    float cim = (ci * lre - cr * lim) / den;
    consts[n] = Are; consts[32 + n] = Aim; consts[64 + n] = cre; consts[96 + n] = cim;
  }
}

// ---------------------------------------------------------------------------
// Kernel 0b: Bbar_t[d][j] (d-major, j = 2n(+1) for re/im of B_bar[n][d])
__global__ void k_bbar(const float* __restrict__ Bre, const float* __restrict__ Bim,
                       const float* __restrict__ consts, float* __restrict__ bbar_t) {
  int idx = blockIdx.x * 256 + threadIdx.x;  // DM*NJ = 131072
  int d = idx >> 6, j = idx & 63, n = j >> 1;
  float cre = consts[64 + n], cim = consts[96 + n];
  float br = Bre[n * DM + d], bi = Bim[n * DM + d];
  float v = (j & 1) ? (cre * bi + cim * br) : (cre * br - cim * bi);
  bbar_t[idx] = v;
}

// Kernel 0c: Cc_t[j][d]: j even -> 2*C_re[d][n], j odd -> -2*C_im[d][n]
__global__ void k_cc(const float* __restrict__ Cre, const float* __restrict__ Cim,
                     float* __restrict__ cc_t) {
  int idx = blockIdx.x * 256 + threadIdx.x;  // NJ*DM = 131072
  int j = idx >> 11, d = idx & 2047, n = j >> 1;
  float v = (j & 1) ? (-2.f * Cim[d * 32 + n]) : (2.f * Cre[d * 32 + n]);
  cc_t[idx] = v;
}

// ---------------------------------------------------------------------------
// Kernel 1: Bu partial GEMM.  bu_p[s][row][j] += u[row][k] * Bbar_t[k][j], k in split s.
// Block: 64 rows x 64 j, K-tiles of 64, 4x4 register tile per thread.
__global__ __launch_bounds__(256) void k_bu(const float* __restrict__ u,
                                            const float* __restrict__ bbar_t,
                                            float* __restrict__ bu_p) {
  __shared__ __align__(16) float As[64][68];  // [k][row]  (transposed u tile)
  __shared__ __align__(16) float Bs[64][68];  // [k][j]
  const int t = threadIdx.x;
  const int m0 = blockIdx.x * 64;
  const int ks0 = blockIdx.y * (DM / KSPLIT);  // 512-wide K window
  const int q = t & 15;    // float4 index within a 64-wide row
  const int rb = t >> 4;   // 0..15
  const int tm = t & 15;   // row group (4 rows)
  const int tn = t >> 4;   // col group (4 cols)
  float acc[4][4] = {};
  for (int kt = 0; kt < 8; ++kt) {
    const int k0 = ks0 + kt * 64;
    // Stage A (u), transposing to k-major. Coalesced 256B global reads.
#pragma unroll
    for (int m = 0; m < 4; ++m) {
      const int row = rb + 16 * m;
      float4 v = *(const float4*)&u[(size_t)(m0 + row) * DM + k0 + 4 * q];
      As[4 * q + 0][row] = v.x;
      As[4 * q + 1][row] = v.y;
      As[4 * q + 2][row] = v.z;
      As[4 * q + 3][row] = v.w;
    }
    // Stage B (Bbar_t), already k-major: direct float4.
#pragma unroll
    for (int m = 0; m < 4; ++m) {
      const int kk = rb + 16 * m;
      *(float4*)&Bs[kk][4 * q] = *(const float4*)&bbar_t[(size_t)(k0 + kk) * NJ + 4 * q];
    }
    __syncthreads();
#pragma unroll 8
    for (int k = 0; k < 64; ++k) {
      float4 av = *(const float4*)&As[k][4 * tm];
      float4 bv = *(const float4*)&Bs[k][4 * tn];
      float aa[4] = {av.x, av.y, av.z, av.w};
      float bb[4] = {bv.x, bv.y, bv.z, bv.w};
#pragma unroll
      for (int i = 0; i < 4; ++i)
#pragma unroll
        for (int j = 0; j < 4; ++j)
          acc[i][j] += aa[i] * bb[j];
    }
    __syncthreads();
  }
  // Epilogue: row-major partials, float4 stores (fully granule-aligned).
  float* outp = bu_p + (size_t)blockIdx.y * M_ROWS * NJ;
#pragma unroll
  for (int i = 0; i < 4; ++i) {
    const int row = m0 + 4 * tm + i;
    float4 v = make_float4(acc[i][0], acc[i][1], acc[i][2], acc[i][3]);
    *(float4*)&outp[(size_t)row * NJ + 4 * tn] = v;
  }
}

// ---------------------------------------------------------------------------
// Kernel 2: associative scan along L for each (b, n). Block = one sequence.
// x_t = A*x_{t-1} + Bu_t (complex). 16 local steps/thread + Hillis carry scan
// (uniform multiplier M = A^16). Writes xs_t[2n][row], xs_t[2n+1][row] (j-major).
__global__ __launch_bounds__(256) void k_scan(const float* __restrict__ bu_p,
                                              const float* __restrict__ consts,
                                              float* __restrict__ xs_t) {
  __shared__ float2 sbuf[L_SEQ + 256];  // padded: idx' = idx + (idx>>4)
  __shared__ float2 P[256];
  const int n = blockIdx.x;  // 0..31
  const int b = blockIdx.y;  // 0..3
  const int t = threadIdx.x;
  const size_t base = (size_t)b * L_SEQ;
  const float Are = consts[n], Aim = consts[32 + n];
  // Load + sum the 4 K-split partials (coalesced in i, strided in j: small data).
  for (int i = t; i < L_SEQ; i += 256) {
    const size_t row = base + i;
    float re = 0.f, im = 0.f;
#pragma unroll
    for (int s = 0; s < KSPLIT; ++s) {
      float2 v = *(const float2*)&bu_p[((size_t)s * M_ROWS + row) * NJ + 2 * n];
      re += v.x; im += v.y;
    }
    sbuf[i + (i >> 4)] = make_float2(re, im);
  }
  __syncthreads();
  // Local inclusive scan of 16 consecutive elements.
  float lre[16], lim[16];
  float xre = 0.f, xim = 0.f;
#pragma unroll
  for (int i = 0; i < 16; ++i) {
    float2 bu = sbuf[17 * t + i];
    float nr = Are * xre - Aim * xim + bu.x;
    float ni = Are * xim + Aim * xre + bu.y;
    xre = nr; xim = ni;
    lre[i] = nr; lim[i] = ni;
  }
  // M = A^16 by repeated squaring.
  float Mre = Are, Mim = Aim;
#pragma unroll
  for (int k = 0; k < 4; ++k) {
    float nr = Mre * Mre - Mim * Mim;
    float ni = 2.f * Mre * Mim;
    Mre = nr; Mim = ni;
  }
  // Hillis-Steele inclusive scan of carries: P_t = carry_t + M * P_{t-1}.
  float pre = xre, pim = xim;
  P[t] = make_float2(pre, pim);
  __syncthreads();
  float msre = Mre, msim = Mim;  // M^s
  for (int s = 1; s < 256; s <<= 1) {
    float2 prev = (t >= s) ? P[t - s] : make_float2(0.f, 0.f);
    __syncthreads();
    pre += msre * prev.x - msim * prev.y;
    pim += msre * prev.y + msim * prev.x;
    P[t] = make_float2(pre, pim);
    float nr = msre * msre - msim * msim;
    float ni = 2.f * msre * msim;
    msre = nr; msim = ni;
    __syncthreads();
  }
  float2 E = (t == 0) ? make_float2(0.f, 0.f) : P[t - 1];
  // Apply: x_i_final = local_i + A^{i+1} * E; stash back to LDS for coalesced store.
  float pwre = Are, pwim = Aim;
#pragma unroll
  for (int i = 0; i < 16; ++i) {
    float rre = lre[i] + pwre * E.x - pwim * E.y;
    float rim = lim[i] + pwre * E.y + pwim * E.x;
    sbuf[17 * t + i] = make_float2(rre, rim);
    float nr = pwre * Are - pwim * Aim;
    float ni = pwre * Aim + pwim * Are;
    pwre = nr; pwim = ni;
  }
  __syncthreads();
  float* r0 = xs_t + (size_t)(2 * n) * M_ROWS + base;
  float* r1 = xs_t + (size_t)(2 * n + 1) * M_ROWS + base;
  for (int i = t; i < L_SEQ; i += 256) {
    float2 v = sbuf[i + (i >> 4)];
    r0[i] = v.x;
    r1[i] = v.y;
  }
}

// ---------------------------------------------------------------------------
// Kernel 3: y[row][d] = sum_j xs_t[j][row] * Cc_t[j][d] + D[d]*u[row][d]
// (2x and -sign folded into Cc_t). Block: 64 rows x 64 d, K=64 in one tile.
__global__ __launch_bounds__(256) void k_out(const float* __restrict__ xs_t,
                                             const float* __restrict__ cc_t,
                                             const float* __restrict__ u,
                                             const float* __restrict__ Dv,
                                             float* __restrict__ y) {
  __shared__ __align__(16) float As[64][68];  // [j][row]
  __shared__ __align__(16) float Bs[64][68];  // [j][d]
  const int t = threadIdx.x;
  const int m0 = blockIdx.x * 64;
  const int d0 = blockIdx.y * 64;
  const int q = t & 15;
  const int rb = t >> 4;
#pragma unroll
  for (int m = 0; m < 4; ++m) {
    const int j = rb + 16 * m;
    *(float4*)&As[j][4 * q] = *(const float4*)&xs_t[(size_t)j * M_ROWS + m0 + 4 * q];
    *(float4*)&Bs[j][4 * q] = *(const float4*)&cc_t[(size_t)j * DM + d0 + 4 * q];
  }
  __syncthreads();
  const int tm = t & 15;
  const int tn = t >> 4;
  float acc[4][4] = {};
#pragma unroll 8
  for (int j = 0; j < 64; ++j) {
    float4 av = *(const float4*)&As[j][4 * tm];
    float4 bv = *(const float4*)&Bs[j][4 * tn];
    float aa[4] = {av.x, av.y, av.z, av.w};
    float bb[4] = {bv.x, bv.y, bv.z, bv.w};
#pragma unroll
    for (int i = 0; i < 4; ++i)
#pragma unroll
      for (int jj = 0; jj < 4; ++jj)
        acc[i][jj] += aa[i] * bb[jj];
  }
  float4 dv = *(const float4*)&Dv[d0 + 4 * tn];
  float dd[4] = {dv.x, dv.y, dv.z, dv.w};
#pragma unroll
  for (int i = 0; i < 4; ++i) {
    const size_t row = (size_t)(m0 + 4 * tm + i);
    float4 uv = *(const float4*)&u[row * DM + d0 + 4 * tn];
    float4 o;
    o.x = acc[i][0] + dd[0] * uv.x;
    o.y = acc[i][1] + dd[1] * uv.y;
    o.z = acc[i][2] + dd[2] * uv.z;
    o.w = acc[i][3] + dd[3] * uv.w;
    *(float4*)&y[row * DM + d0 + 4 * tn] = o;
  }
}

// ---------------------------------------------------------------------------
extern "C" void kernel_launch(void* const* d_in, const int* in_sizes, int n_in,
                              void* d_out, int out_size, void* d_ws, size_t ws_size,
                              hipStream_t stream) {
  const float* u      = (const float*)d_in[0];
  const float* lam_ur = (const float*)d_in[1];
  const float* lam_im = (const float*)d_in[2];
  const float* B_re   = (const float*)d_in[3];
  const float* B_im   = (const float*)d_in[4];
  const float* C_re   = (const float*)d_in[5];
  const float* C_im   = (const float*)d_in[6];
  const float* Dv     = (const float*)d_in[7];
  const float* log_dt = (const float*)d_in[8];
  float* y  = (float*)d_out;
  float* ws = (float*)d_ws;

  float* consts = ws + O_CONSTS;
  float* bbar_t = ws + O_BBAR;
  float* cc_t   = ws + O_CC;
  float* bu_p   = ws + O_BUP;
  float* xs_t   = ws + O_XS;

  k_setup<<<1, 64, 0, stream>>>(lam_ur, lam_im, log_dt, consts);
  k_bbar<<<(DM * NJ) / 256, 256, 0, stream>>>(B_re, B_im, consts, bbar_t);
  k_cc<<<(NJ * DM) / 256, 256, 0, stream>>>(C_re, C_im, cc_t);
  k_bu<<<dim3(M_ROWS / 64, KSPLIT), 256, 0, stream>>>(u, bbar_t, bu_p);
  k_scan<<<dim3(32, 4), 256, 0, stream>>>(bu_p, consts, xs_t);
  k_out<<<dim3(M_ROWS / 64, DM / 64), 256, 0, stream>>>(xs_t, cc_t, u, Dv, y);
}